// Round 10
// baseline (321.761 us; speedup 1.0000x reference)
//
#include <hip/hip_runtime.h>
#include <math.h>

// ---------------------------------------------------------------------------
// Decoder block: x -> QKV proj -> causal MHA -> a + LN(a) -> FFN -> f + LN(f)
// B=2 T=2048 C=1024 NH=16 hd=64 DFF=4096, fp32 in/out.
// Round 24:
//   * R23: fattn line/swizzle fix real (~15 us clock-normalized); run had
//     ~12% lower clock (unchanged FFN2 59.9->70 us, hbm_gbps -14%).
//   * Two remaining mechanism-understood levers, both session-proven:
//     1) prep transpose wrote 64 B half-lines (same disease R20 cured):
//        -> 64x64 tiles, 128 B full-line bf16 writes, [64][65] LDS
//        (2 lanes/bank = free). Grid 15368 -> 6920.
//     2) FFN2 at 512 blocks = 2/CU is concurrency-starved (12.8 TB/s vs
//        15.4 at 8/CU). Split-K=2 at <128,64> -> 1024 blocks = 4/CU;
//        partials summed in the final add_ln (in2 path).
//   * GEMM body/tiles, fattn, add_ln reduce unchanged.
// ---------------------------------------------------------------------------

typedef __attribute__((ext_vector_type(8))) short short8;
typedef __attribute__((ext_vector_type(4))) float f32x4;

__device__ __forceinline__ unsigned short f2bf(float f) {
    unsigned u = __builtin_bit_cast(unsigned, f);
    unsigned r = u + 0x7fffu + ((u >> 16) & 1u);   // RNE
    return (unsigned short)(r >> 16);
}

// ---------------------------------------------------------------------------
// Merged preprocessing. Grid = 6920 blocks of 256.
//   [0,4096)      x fp32 -> bf16
//   [4096,4352)   Wq transpose   [4352,4608) Wk   [4608,4864) Wv
//   [4864,5888)   W1 transpose   [5888,6912) W2
//   [6912,6920)   bias concat
// 64x64 transpose tiles: 256 B/row reads, 128 B/row bf16 writes (full lines).
// ---------------------------------------------------------------------------
__global__ __launch_bounds__(256) void prep_kernel(
    const float* __restrict__ x,  const float* __restrict__ Wq,
    const float* __restrict__ Wk, const float* __restrict__ Wv,
    const float* __restrict__ W1, const float* __restrict__ W2,
    const float* __restrict__ bq, const float* __restrict__ bk,
    unsigned short* __restrict__ x_bf,  unsigned short* __restrict__ Wqk_t,
    unsigned short* __restrict__ Wvt,   unsigned short* __restrict__ W1t,
    unsigned short* __restrict__ W2t,   float* __restrict__ bqk)
{
    const int bid = blockIdx.x;
    const int tid = threadIdx.x;

    if (bid < 4096) {                       // x convert
        const int i = (bid * 256 + tid) * 4;
        float4 v = *(const float4*)(x + i);
        ushort4 o;
        o.x = f2bf(v.x); o.y = f2bf(v.y); o.z = f2bf(v.z); o.w = f2bf(v.w);
        *(ushort4*)(x_bf + i) = o;
        return;
    }
    if (bid >= 6912) {                      // bias concat
        const int i = (bid - 6912) * 256 + tid;
        bqk[i] = i < 1024 ? bq[i] : bk[i - 1024];
        return;
    }

    __shared__ float tile[64][65];
    const float* src; unsigned short* dst; int K, N, t;
    if (bid < 4352)      { t = bid - 4096; src = Wq; dst = Wqk_t;           K = 1024; N = 1024; }
    else if (bid < 4608) { t = bid - 4352; src = Wk; dst = Wqk_t + 1048576; K = 1024; N = 1024; }
    else if (bid < 4864) { t = bid - 4608; src = Wv; dst = Wvt;             K = 1024; N = 1024; }
    else if (bid < 5888) { t = bid - 4864; src = W1; dst = W1t;             K = 1024; N = 4096; }
    else                 { t = bid - 5888; src = W2; dst = W2t;             K = 4096; N = 1024; }

    const int ncols = N >> 6;
    const int n0 = (t % ncols) * 64;
    const int k0 = (t / ncols) * 64;
    const int tx = tid & 15;                // 16 lanes x float4 = 64 cols
    const int ty = tid >> 4;                // 0..15
#pragma unroll
    for (int i = 0; i < 4; ++i) {
        const int r = ty + i * 16;
        float4 v = *(const float4*)(src + (size_t)(k0 + r) * N + n0 + tx * 4);
        tile[r][tx * 4 + 0] = v.x;
        tile[r][tx * 4 + 1] = v.y;
        tile[r][tx * 4 + 2] = v.z;
        tile[r][tx * 4 + 3] = v.w;
    }
    __syncthreads();
#pragma unroll
    for (int i = 0; i < 4; ++i) {
        const int n = ty + i * 16;
        ushort4 o;
        o.x = f2bf(tile[tx * 4 + 0][n]);
        o.y = f2bf(tile[tx * 4 + 1][n]);
        o.z = f2bf(tile[tx * 4 + 2][n]);
        o.w = f2bf(tile[tx * 4 + 3][n]);
        *(ushort4*)(dst + (size_t)(n0 + n) * K + k0 + tx * 4) = o;
    }
}

// ---------------------------------------------------------------------------
// GEMM body: C[M][N] = A[M][K] . Bt[N][K]^T + bias over K in [kbeg,kend).
// 1-phase 2-barrier loop, BK=64. LDS: [rows][64] shorts, staged in 8-row
// panels, 128 B/row (full cache lines). Both-sides XOR swizzle: source
// col-slot (lane&7)^(lane>>3), read slot col16 ^ (row&7).
// mode: 0 = fp32 out, bias[col]; 1 = relu->bf16, bias[col];
//       2 = bf16, bias[col];     3 = bf16, bias[row]; 4 = fp32, no bias.
// ---------------------------------------------------------------------------
template <int TM, int TN>
__device__ __forceinline__ void gemm_body(
    unsigned short* As, unsigned short* Bs,
    const unsigned short* __restrict__ A, const unsigned short* __restrict__ Bt,
    const float* __restrict__ bias, float* __restrict__ Cf,
    unsigned short* __restrict__ Cb, int M, int N, int K, int mode,
    int bx, int by, int kbeg, int kend)
{
    constexpr int NI   = TM / 32;
    constexpr int NJ   = TN / 32;
    constexpr int NPA  = TM / 8;            // 8-row panels
    constexpr int NPB  = TN / 8;
    constexpr int MAXA = (NPA + 3) / 4;
    constexpr int MAXB = (NPB + 3) / 4;

    const int tid  = threadIdx.x;
    const int lane = tid & 63;
    const int w    = tid >> 6;
    const int wm   = (w & 1) * (TM / 2);
    const int wn   = (w >> 1) * (TN / 2);
    const int fm   = lane & 15;
    const int quad = lane >> 4;

    const int row0 = by * TM;
    const int col0 = bx * TN;

    // Staging lane geometry: 8 rows x 128 B contiguous, source pre-swizzled.
    const int srow = lane >> 3;                  // 0..7
    const int scol = ((lane & 7) ^ srow) << 3;   // swizzled col (shorts)

    const unsigned short* aptr[MAXA];
    int aoff[MAXA];
#pragma unroll
    for (int i = 0; i < MAXA; ++i) {
        const int p = w + i * 4;
        if (p < NPA) {
            aptr[i] = A + (size_t)(row0 + p * 8 + srow) * K + scol;
            aoff[i] = p * 8 * 64;                // shorts
        }
    }
    const unsigned short* bptr[MAXB];
    int boff[MAXB];
#pragma unroll
    for (int i = 0; i < MAXB; ++i) {
        const int p = w + i * 4;
        if (p < NPB) {
            bptr[i] = Bt + (size_t)(col0 + p * 8 + srow) * K + scol;
            boff[i] = p * 8 * 64;
        }
    }

    f32x4 acc[NI][NJ] = {};

    for (int k0 = kbeg; k0 < kend; k0 += 64) {
        __syncthreads();
#pragma unroll
        for (int i = 0; i < MAXA; ++i)
            if (w + i * 4 < NPA)          // wave-uniform
                __builtin_amdgcn_global_load_lds(
                    (const __attribute__((address_space(1))) void*)(aptr[i] + k0),
                    (__attribute__((address_space(3))) void*)&As[aoff[i]], 16, 0, 0);
#pragma unroll
        for (int i = 0; i < MAXB; ++i)
            if (w + i * 4 < NPB)          // wave-uniform
                __builtin_amdgcn_global_load_lds(
                    (const __attribute__((address_space(1))) void*)(bptr[i] + k0),
                    (__attribute__((address_space(3))) void*)&Bs[boff[i]], 16, 0, 0);
        __syncthreads();

#pragma unroll
        for (int kh = 0; kh < 2; ++kh) {
            short8 af[NI], bf[NJ];
#pragma unroll
            for (int i = 0; i < NI; ++i) {
                const int r = wm + i * 16 + fm;
                const int sl = ((kh << 2) | quad) ^ (r & 7);
                af[i] = *(const short8*)&As[r * 64 + sl * 8];
            }
#pragma unroll
            for (int j = 0; j < NJ; ++j) {
                const int r = wn + j * 16 + fm;
                const int sl = ((kh << 2) | quad) ^ (r & 7);
                bf[j] = *(const short8*)&Bs[r * 64 + sl * 8];
            }
#pragma unroll
            for (int i = 0; i < NI; ++i)
#pragma unroll
                for (int j = 0; j < NJ; ++j)
                    acc[i][j] = __builtin_amdgcn_mfma_f32_16x16x32_bf16(
                        af[i], bf[j], acc[i][j], 0, 0, 0);
        }
    }

    // Epilogue. C/D layout: col = lane&15, row = quad*4 + reg.
#pragma unroll
    for (int j = 0; j < NJ; ++j) {
        const int col = col0 + wn + j * 16 + fm;
        const float bcol = (mode == 3 || mode == 4) ? 0.f : bias[col];
#pragma unroll
        for (int i = 0; i < NI; ++i) {
            const int rbase = row0 + wm + i * 16 + quad * 4;
#pragma unroll
            for (int r = 0; r < 4; ++r) {
                const int row = rbase + r;
                float val = acc[i][j][r] + ((mode == 3) ? bias[row] : bcol);
                if (mode == 1) val = fmaxf(val, 0.f);
                if (mode == 0 || mode == 4) Cf[(size_t)row * N + col] = val;
                else                        Cb[(size_t)row * N + col] = f2bf(val);
            }
        }
    }
}

template <int TM, int TN>
__global__ __launch_bounds__(256) void gemm_bf16_mfma(
    const unsigned short* __restrict__ A, const unsigned short* __restrict__ Bt,
    const float* __restrict__ bias, float* __restrict__ Cf,
    unsigned short* __restrict__ Cb, int M, int N, int K, int mode)
{
    __shared__ unsigned short As[TM * 64];
    __shared__ unsigned short Bs[TN * 64];
    gemm_body<TM, TN>(As, Bs, A, Bt, bias, Cf, Cb, M, N, K, mode,
                      blockIdx.x, blockIdx.y, 0, K);
}

// Split-K=2 GEMM with XCD row-striping: blocks [0,nbh) -> K low half -> C0
// (mode 0, bias); [nbh,2*nbh) -> high half -> C1 (mode 4). nbh % 8 == 0.
template <int TM, int TN>
__global__ __launch_bounds__(256) void gemm_splitk(
    const unsigned short* __restrict__ A, const unsigned short* __restrict__ Bt,
    const float* __restrict__ bias, float* __restrict__ C0,
    float* __restrict__ C1, int M, int N, int K,
    int nxh, int rows_per_xcd_h, int nbh)
{
    __shared__ unsigned short As[TM * 64];
    __shared__ unsigned short Bs[TN * 64];
    const int half = blockIdx.x >= nbh;
    const int r    = blockIdx.x - (half ? nbh : 0);
    const int xcd  = blockIdx.x & 7;
    const int idx  = r >> 3;
    const int bx   = idx % nxh;
    const int by   = xcd * rows_per_xcd_h + idx / nxh;
    const int kb   = half ? (K >> 1) : 0;
    gemm_body<TM, TN>(As, Bs, A, Bt, bias, half ? C1 : C0, nullptr,
                      M, N, K, half ? 4 : 0, bx, by, kb, kb + (K >> 1));
}

// Two independent GEMMs (same tile config) in one flat-grid dispatch.
template <int TM, int TN>
__global__ __launch_bounds__(256) void gemm_dual(
    const unsigned short* __restrict__ A0, const unsigned short* __restrict__ B0,
    const float* __restrict__ bias0, unsigned short* __restrict__ C0,
    int M0, int N0, int K0, int mode0, int nb0, int nx0,
    const unsigned short* __restrict__ A1, const unsigned short* __restrict__ B1,
    const float* __restrict__ bias1, unsigned short* __restrict__ C1,
    int M1, int N1, int K1, int mode1, int nx1)
{
    __shared__ unsigned short As[TM * 64];
    __shared__ unsigned short Bs[TN * 64];
    const int bid = blockIdx.x;
    if (bid < nb0) {
        gemm_body<TM, TN>(As, Bs, A0, B0, bias0, nullptr, C0,
                          M0, N0, K0, mode0, bid % nx0, bid / nx0, 0, K0);
    } else {
        const int t = bid - nb0;
        gemm_body<TM, TN>(As, Bs, A1, B1, bias1, nullptr, C1,
                          M1, N1, K1, mode1, t % nx1, t / nx1, 0, K1);
    }
}

// ---------------------------------------------------------------------------
// MFMA flash attention v3. qk: [4096][2048] bf16 (q cols 0..1023, k 1024..),
// vt: [1024][4096] bf16 (row = h*64+d, col = b*2048+t), a: [4096][1024] fp32.
// Q/K/V LDS = [64][64] shorts (hd=64 -> 128 B full-line rows), staged as
// 8-row x 128 B panels with both-sides XOR swizzle (R20 pattern).
// ---------------------------------------------------------------------------
__global__ __launch_bounds__(256) void fattn_mfma(
    const unsigned short* __restrict__ qk,
    const unsigned short* __restrict__ vt,
    float* __restrict__ a)
{
    const int T = 2048, LDQK = 2048, LDVT = 4096, OUTC = 1024;
    const float cs = 0.04508422f;       // (1/32) * log2(e)

    __shared__ unsigned short Qs[64 * 64];
    __shared__ unsigned short Ks[64 * 64];
    __shared__ unsigned short Vs[64 * 64];
    __shared__ unsigned short Ps[4][16][72];

    const int tid  = threadIdx.x;
    const int lane = tid & 63;
    const int w    = tid >> 6;
    const int fm   = lane & 15;
    const int quad = lane >> 4;
    const int srow = lane >> 3;                  // 0..7
    const int scol = ((lane & 7) ^ srow) << 3;   // swizzled col (shorts)

    const int n  = blockIdx.x;
    const int lo = n & 255, hi = n >> 8;
    const int h  = ((lo >> 5) & 7) | ((hi & 1) << 3);
    const int b  = hi >> 1;
    const int qv = lo & 31;
    const int u  = ((qv & 1) << 4) | ((qv & 2) << 2) | (qv & 4) |
                   ((qv & 8) >> 2) | ((qv & 16) >> 4);
    const int qb = (hi & 1) ? (31 - u) : u;
    const int q0 = qb * 64;

    const size_t rowbase = (size_t)b * T;

    // Q stage: 8 panels of 8 rows x 128 B; wave w stages panels w*2, w*2+1.
#pragma unroll
    for (int i = 0; i < 2; ++i) {
        const int p = w * 2 + i;
        const unsigned short* src = qk + (rowbase + q0 + p * 8 + srow) * LDQK
                                       + h * 64 + scol;
        __builtin_amdgcn_global_load_lds(
            (const __attribute__((address_space(1))) void*)src,
            (__attribute__((address_space(3))) void*)&Qs[p * 8 * 64], 16, 0, 0);
    }
    __syncthreads();
    const int qr = w * 16 + fm;
    short8 qf0 = *(const short8*)&Qs[qr * 64 + ((quad ^ (qr & 7)) << 3)];
    short8 qf1 = *(const short8*)&Qs[qr * 64 + (((4 | quad) ^ (qr & 7)) << 3)];

    short8 ones;
#pragma unroll
    for (int i = 0; i < 8; ++i) ones[i] = (short)0x3F80;   // bf16 1.0

    f32x4 o[4] = {};
    f32x4 lacc = {};

    const int qglob = q0 + w * 16 + fm;

    for (int jt = 0; jt <= qb; ++jt) {
        const int j0 = jt * 64;
        __syncthreads();
        // K: 8 panels, V: 8 panels; wave w stages units w*4 .. w*4+3.
#pragma unroll
        for (int i = 0; i < 4; ++i) {
            const int unit = w * 4 + i;          // wave-uniform
            if (unit < 8) {
                const unsigned short* ksrc = qk + (rowbase + j0 + unit * 8 + srow) * LDQK
                                                + 1024 + h * 64 + scol;
                __builtin_amdgcn_global_load_lds(
                    (const __attribute__((address_space(1))) void*)ksrc,
                    (__attribute__((address_space(3))) void*)&Ks[unit * 8 * 64], 16, 0, 0);
            } else {
                const int p = unit - 8;
                const unsigned short* vsrc = vt + (size_t)(h * 64 + p * 8 + srow) * LDVT
                                                + rowbase + j0 + scol;
                __builtin_amdgcn_global_load_lds(
                    (const __attribute__((address_space(1))) void*)vsrc,
                    (__attribute__((address_space(3))) void*)&Vs[p * 8 * 64], 16, 0, 0);
            }
        }
        __syncthreads();

        // S^T = K . Q^T
        f32x4 s[4];
#pragma unroll
        for (int j = 0; j < 4; ++j) {
            const int r = j * 16 + fm;
            short8 k0 = *(const short8*)&Ks[r * 64 + ((quad ^ (r & 7)) << 3)];
            short8 k1 = *(const short8*)&Ks[r * 64 + (((4 | quad) ^ (r & 7)) << 3)];
            f32x4 acc = {};
            acc = __builtin_amdgcn_mfma_f32_16x16x32_bf16(k0, qf0, acc, 0, 0, 0);
            acc = __builtin_amdgcn_mfma_f32_16x16x32_bf16(k1, qf1, acc, 0, 0, 0);
            s[j] = acc;
        }

        if (jt == qb) {
#pragma unroll
            for (int j = 0; j < 4; ++j) {
                const int kbase = j0 + j * 16 + quad * 4;
#pragma unroll
                for (int r = 0; r < 4; ++r) {
                    const float e = exp2f(s[j][r] * cs);
                    s[j][r] = (kbase + r > qglob) ? 0.f : e;
                }
            }
        } else {
#pragma unroll
            for (int j = 0; j < 4; ++j)
#pragma unroll
                for (int r = 0; r < 4; ++r)
                    s[j][r] = exp2f(s[j][r] * cs);
        }

#pragma unroll
        for (int j = 0; j < 4; ++j) {
            const unsigned d0 = (unsigned)f2bf(s[j][0]) | ((unsigned)f2bf(s[j][1]) << 16);
            const unsigned d1 = (unsigned)f2bf(s[j][2]) | ((unsigned)f2bf(s[j][3]) << 16);
            *(uint2*)&Ps[w][fm][j * 16 + quad * 4] = make_uint2(d0, d1);
        }
        short8 pf0 = *(const short8*)&Ps[w][fm][quad * 8];
        short8 pf1 = *(const short8*)&Ps[w][fm][32 + quad * 8];

#pragma unroll
        for (int jd = 0; jd < 4; ++jd) {
            const int r = jd * 16 + fm;
            short8 v0 = *(const short8*)&Vs[r * 64 + ((quad ^ (r & 7)) << 3)];
            short8 v1 = *(const short8*)&Vs[r * 64 + (((4 | quad) ^ (r & 7)) << 3)];
            o[jd] = __builtin_amdgcn_mfma_f32_16x16x32_bf16(pf0, v0, o[jd], 0, 0, 0);
            o[jd] = __builtin_amdgcn_mfma_f32_16x16x32_bf16(pf1, v1, o[jd], 0, 0, 0);
        }
        lacc = __builtin_amdgcn_mfma_f32_16x16x32_bf16(pf0, ones, lacc, 0, 0, 0);
        lacc = __builtin_amdgcn_mfma_f32_16x16x32_bf16(pf1, ones, lacc, 0, 0, 0);
    }

    const size_t orow = rowbase + q0 + w * 16 + quad * 4;
#pragma unroll
    for (int r = 0; r < 4; ++r) {
        const float inv = 1.0f / lacc[r];
#pragma unroll
        for (int jd = 0; jd < 4; ++jd)
            a[(orow + r) * OUTC + h * 64 + jd * 16 + fm] = o[jd][r] * inv;
    }
}

// out = in (+ in2) + LayerNorm(in (+ in2))*w.
// bf16_out=1 -> write bf16 to outb, else fp32 outf. Wave-shuffle reduction.
__global__ __launch_bounds__(256) void add_ln_kernel(
    const float* __restrict__ in, const float* __restrict__ in2,
    const float* __restrict__ w,
    float* __restrict__ outf, unsigned short* __restrict__ outb, int bf16_out)
{
    const int C = 1024;
    const int row = blockIdx.x;
    const int tid = threadIdx.x;
    const int lane = tid & 63;
    const int wv   = tid >> 6;

    __shared__ float red[8];

    float4 xv = *(const float4*)(in + (size_t)row * C + tid * 4);
    if (in2) {
        float4 yv = *(const float4*)(in2 + (size_t)row * C + tid * 4);
        xv.x += yv.x; xv.y += yv.y; xv.z += yv.z; xv.w += yv.w;
    }

    float s = xv.x + xv.y + xv.z + xv.w;
#pragma unroll
    for (int o = 32; o > 0; o >>= 1) s += __shfl_xor(s, o, 64);
    if (lane == 0) red[wv] = s;
    __syncthreads();
    const float mu = (red[0] + red[1] + red[2] + red[3]) * (1.0f / 1024.0f);

    float dx = xv.x - mu, dy = xv.y - mu, dz = xv.z - mu, dw = xv.w - mu;
    float v = dx * dx + dy * dy + dz * dz + dw * dw;
#pragma unroll
    for (int o = 32; o > 0; o >>= 1) v += __shfl_xor(v, o, 64);
    if (lane == 0) red[4 + wv] = v;
    __syncthreads();
    const float rstd = rsqrtf((red[4] + red[5] + red[6] + red[7]) * (1.0f / 1024.0f)
                              + 1e-5f);

    float4 wvv = *(const float4*)(w + tid * 4);
    float ox = xv.x + dx * rstd * wvv.x;
    float oy = xv.y + dy * rstd * wvv.y;
    float oz = xv.z + dz * rstd * wvv.z;
    float ow = xv.w + dw * rstd * wvv.w;
    if (bf16_out) {
        ushort4 o4;
        o4.x = f2bf(ox); o4.y = f2bf(oy); o4.z = f2bf(oz); o4.w = f2bf(ow);
        *(ushort4*)(outb + (size_t)row * C + tid * 4) = o4;
    } else {
        *(float4*)(outf + (size_t)row * C + tid * 4) = make_float4(ox, oy, oz, ow);
    }
}

extern "C" void kernel_launch(void* const* d_in, const int* in_sizes, int n_in,
                              void* d_out, int out_size, void* d_ws, size_t ws_size,
                              hipStream_t stream)
{
    const float* x    = (const float*)d_in[0];
    const float* Wq   = (const float*)d_in[1];
    const float* bq   = (const float*)d_in[2];
    const float* Wk   = (const float*)d_in[3];
    const float* bk   = (const float*)d_in[4];
    const float* Wv   = (const float*)d_in[5];
    const float* bv   = (const float*)d_in[6];
    const float* W1   = (const float*)d_in[7];
    const float* b1   = (const float*)d_in[8];
    const float* W2   = (const float*)d_in[9];
    const float* b2   = (const float*)d_in[10];
    const float* ln_w = (const float*)d_in[11];
    float* out = (float*)d_out;
    char* ws = (char*)d_ws;

    const int B = 2, T = 2048, C = 1024, DFF = 4096;
    const int M = B * T;                 // 4096
    const size_t MB = 1048576;

    unsigned short* qk_bf = (unsigned short*)(ws);             // 16 MB [4096][2048]
    unsigned short* vt_bf = (unsigned short*)(ws + 16 * MB);   //  8 MB [1024][4096]
    float*          a     = (float*)(ws + 24 * MB);            // 16 MB [4096][1024]
    unsigned short* x_bf  = (unsigned short*)(ws + 40 * MB);   //  8 MB [4096][1024]
    unsigned short* Wqk_t = (unsigned short*)(ws + 48 * MB);   //  4 MB [2048][1024]
    unsigned short* Wvt   = (unsigned short*)(ws + 52 * MB);   //  2 MB [1024][1024]
    unsigned short* W1t   = (unsigned short*)(ws + 54 * MB);   //  8 MB [4096][1024]
    unsigned short* W2t   = (unsigned short*)(ws + 62 * MB);   //  8 MB [1024][4096]
    float*          bqk   = (float*)(ws + 70 * MB);            //  8 KB [2048]
    unsigned short* u_bf  = (unsigned short*)(ws + 71 * MB);   // 32 MB [4096][4096]
    unsigned short* h_bf  = x_bf;                              // reuse (x dead)
    float*          f     = (float*)(ws);                      // 16 MB, reuse qk (dead)
    float*          f2    = a;                                 // 16 MB, reuse a  (dead)

    dim3 blk(256);

    // One merged preprocessing dispatch (full-line transpose writes).
    prep_kernel<<<dim3(6920), blk, 0, stream>>>(
        x, Wq, Wk, Wv, W1, W2, bq, bk,
        x_bf, Wqk_t, Wvt, W1t, W2t, bqk);

    // QK projection + V^T in one dual dispatch, both <64,128> BK=64.
    gemm_dual<64, 128><<<dim3(1536), blk, 0, stream>>>(
        x_bf, Wqk_t, bqk, qk_bf, M, 2 * C, C, 2, 1024, 16,
        Wvt, x_bf, bv, vt_bf, C, M, C, 3, 32);

    fattn_mfma<<<dim3(1024), blk, 0, stream>>>(qk_bf, vt_bf, a);

    add_ln_kernel<<<dim3(M), blk, 0, stream>>>(a, nullptr, ln_w, nullptr, h_bf, 1);

    // FFN1: [4096,1024] x [1024,4096] -> relu -> bf16. <64,128> BK=64.
    gemm_bf16_mfma<64, 128><<<dim3(DFF / 128, M / 64), blk, 0, stream>>>(
        h_bf, W1t, b1, nullptr, u_bf, M, DFF, C, 1);

    // FFN2: [4096,4096] x [4096,1024] -> fp32, split-K=2. <128,64> BK=64,
    // 1024 blocks = 4/CU (512/half; per-half grid 16 cols x 32 rows,
    // 4 row-tiles per XCD). Partials f + f2 summed in the final add_ln.
    gemm_splitk<128, 64><<<dim3(1024), blk, 0, stream>>>(
        u_bf, W2t, b2, f, f2, M, C, DFF, 16, 4, 512);

    add_ln_kernel<<<dim3(M), blk, 0, stream>>>(f, f2, ln_w, out, nullptr, 0);
}

// Round 11
// 308.604 us; speedup vs baseline: 1.0426x; 1.0426x over previous
//
#include <hip/hip_runtime.h>
#include <math.h>

// ---------------------------------------------------------------------------
// Decoder block: x -> QKV proj -> causal MHA -> a + LN(a) -> FFN -> f + LN(f)
// B=2 T=2048 C=1024 NH=16 hd=64 DFF=4096, fp32 in/out.
// Round 25:
//   * R24 counters: fattn now #1 dispatch (55 us), VALUBusy 49%, Mfma 14%
//     -> VALU-bound. The P->bf16 pack (16 f2bf bit-hacks + or/shift ~80
//     VALU ops/lane/iter) outweighs the 16 v_exp_f32 ~2.5:1.
//   * Fix: pack via v_cvt_pk_bf16_f32 (1 instr / 2 values, RNE like f2bf):
//     8 cvt_pk replace ~80 ops. (m240's warning compared vs a plain cast;
//     our baseline is a bit-hack the compiler can't fuse. T12/m214v22 used
//     this exact primitive for the same step.)
//   * Only fattn touched; R24 base (full-line prep, <64,128> dual/FFN1,
//     split-K FFN2 @4/CU, shuffle add_ln) kept for clean attribution.
// ---------------------------------------------------------------------------

typedef __attribute__((ext_vector_type(8))) short short8;
typedef __attribute__((ext_vector_type(4))) float f32x4;

__device__ __forceinline__ unsigned short f2bf(float f) {
    unsigned u = __builtin_bit_cast(unsigned, f);
    unsigned r = u + 0x7fffu + ((u >> 16) & 1u);   // RNE
    return (unsigned short)(r >> 16);
}

// ---------------------------------------------------------------------------
// Merged preprocessing. Grid = 6920 blocks of 256.
//   [0,4096)      x fp32 -> bf16
//   [4096,4352)   Wq transpose   [4352,4608) Wk   [4608,4864) Wv
//   [4864,5888)   W1 transpose   [5888,6912) W2
//   [6912,6920)   bias concat
// 64x64 transpose tiles: 256 B/row reads, 128 B/row bf16 writes (full lines).
// ---------------------------------------------------------------------------
__global__ __launch_bounds__(256) void prep_kernel(
    const float* __restrict__ x,  const float* __restrict__ Wq,
    const float* __restrict__ Wk, const float* __restrict__ Wv,
    const float* __restrict__ W1, const float* __restrict__ W2,
    const float* __restrict__ bq, const float* __restrict__ bk,
    unsigned short* __restrict__ x_bf,  unsigned short* __restrict__ Wqk_t,
    unsigned short* __restrict__ Wvt,   unsigned short* __restrict__ W1t,
    unsigned short* __restrict__ W2t,   float* __restrict__ bqk)
{
    const int bid = blockIdx.x;
    const int tid = threadIdx.x;

    if (bid < 4096) {                       // x convert
        const int i = (bid * 256 + tid) * 4;
        float4 v = *(const float4*)(x + i);
        ushort4 o;
        o.x = f2bf(v.x); o.y = f2bf(v.y); o.z = f2bf(v.z); o.w = f2bf(v.w);
        *(ushort4*)(x_bf + i) = o;
        return;
    }
    if (bid >= 6912) {                      // bias concat
        const int i = (bid - 6912) * 256 + tid;
        bqk[i] = i < 1024 ? bq[i] : bk[i - 1024];
        return;
    }

    __shared__ float tile[64][65];
    const float* src; unsigned short* dst; int K, N, t;
    if (bid < 4352)      { t = bid - 4096; src = Wq; dst = Wqk_t;           K = 1024; N = 1024; }
    else if (bid < 4608) { t = bid - 4352; src = Wk; dst = Wqk_t + 1048576; K = 1024; N = 1024; }
    else if (bid < 4864) { t = bid - 4608; src = Wv; dst = Wvt;             K = 1024; N = 1024; }
    else if (bid < 5888) { t = bid - 4864; src = W1; dst = W1t;             K = 1024; N = 4096; }
    else                 { t = bid - 5888; src = W2; dst = W2t;             K = 4096; N = 1024; }

    const int ncols = N >> 6;
    const int n0 = (t % ncols) * 64;
    const int k0 = (t / ncols) * 64;
    const int tx = tid & 15;                // 16 lanes x float4 = 64 cols
    const int ty = tid >> 4;                // 0..15
#pragma unroll
    for (int i = 0; i < 4; ++i) {
        const int r = ty + i * 16;
        float4 v = *(const float4*)(src + (size_t)(k0 + r) * N + n0 + tx * 4);
        tile[r][tx * 4 + 0] = v.x;
        tile[r][tx * 4 + 1] = v.y;
        tile[r][tx * 4 + 2] = v.z;
        tile[r][tx * 4 + 3] = v.w;
    }
    __syncthreads();
#pragma unroll
    for (int i = 0; i < 4; ++i) {
        const int n = ty + i * 16;
        ushort4 o;
        o.x = f2bf(tile[tx * 4 + 0][n]);
        o.y = f2bf(tile[tx * 4 + 1][n]);
        o.z = f2bf(tile[tx * 4 + 2][n]);
        o.w = f2bf(tile[tx * 4 + 3][n]);
        *(ushort4*)(dst + (size_t)(n0 + n) * K + k0 + tx * 4) = o;
    }
}

// ---------------------------------------------------------------------------
// GEMM body: C[M][N] = A[M][K] . Bt[N][K]^T + bias over K in [kbeg,kend).
// 1-phase 2-barrier loop, BK=64. LDS: [rows][64] shorts, staged in 8-row
// panels, 128 B/row (full cache lines). Both-sides XOR swizzle: source
// col-slot (lane&7)^(lane>>3), read slot col16 ^ (row&7).
// mode: 0 = fp32 out, bias[col]; 1 = relu->bf16, bias[col];
//       2 = bf16, bias[col];     3 = bf16, bias[row]; 4 = fp32, no bias.
// ---------------------------------------------------------------------------
template <int TM, int TN>
__device__ __forceinline__ void gemm_body(
    unsigned short* As, unsigned short* Bs,
    const unsigned short* __restrict__ A, const unsigned short* __restrict__ Bt,
    const float* __restrict__ bias, float* __restrict__ Cf,
    unsigned short* __restrict__ Cb, int M, int N, int K, int mode,
    int bx, int by, int kbeg, int kend)
{
    constexpr int NI   = TM / 32;
    constexpr int NJ   = TN / 32;
    constexpr int NPA  = TM / 8;            // 8-row panels
    constexpr int NPB  = TN / 8;
    constexpr int MAXA = (NPA + 3) / 4;
    constexpr int MAXB = (NPB + 3) / 4;

    const int tid  = threadIdx.x;
    const int lane = tid & 63;
    const int w    = tid >> 6;
    const int wm   = (w & 1) * (TM / 2);
    const int wn   = (w >> 1) * (TN / 2);
    const int fm   = lane & 15;
    const int quad = lane >> 4;

    const int row0 = by * TM;
    const int col0 = bx * TN;

    // Staging lane geometry: 8 rows x 128 B contiguous, source pre-swizzled.
    const int srow = lane >> 3;                  // 0..7
    const int scol = ((lane & 7) ^ srow) << 3;   // swizzled col (shorts)

    const unsigned short* aptr[MAXA];
    int aoff[MAXA];
#pragma unroll
    for (int i = 0; i < MAXA; ++i) {
        const int p = w + i * 4;
        if (p < NPA) {
            aptr[i] = A + (size_t)(row0 + p * 8 + srow) * K + scol;
            aoff[i] = p * 8 * 64;                // shorts
        }
    }
    const unsigned short* bptr[MAXB];
    int boff[MAXB];
#pragma unroll
    for (int i = 0; i < MAXB; ++i) {
        const int p = w + i * 4;
        if (p < NPB) {
            bptr[i] = Bt + (size_t)(col0 + p * 8 + srow) * K + scol;
            boff[i] = p * 8 * 64;
        }
    }

    f32x4 acc[NI][NJ] = {};

    for (int k0 = kbeg; k0 < kend; k0 += 64) {
        __syncthreads();
#pragma unroll
        for (int i = 0; i < MAXA; ++i)
            if (w + i * 4 < NPA)          // wave-uniform
                __builtin_amdgcn_global_load_lds(
                    (const __attribute__((address_space(1))) void*)(aptr[i] + k0),
                    (__attribute__((address_space(3))) void*)&As[aoff[i]], 16, 0, 0);
#pragma unroll
        for (int i = 0; i < MAXB; ++i)
            if (w + i * 4 < NPB)          // wave-uniform
                __builtin_amdgcn_global_load_lds(
                    (const __attribute__((address_space(1))) void*)(bptr[i] + k0),
                    (__attribute__((address_space(3))) void*)&Bs[boff[i]], 16, 0, 0);
        __syncthreads();

#pragma unroll
        for (int kh = 0; kh < 2; ++kh) {
            short8 af[NI], bf[NJ];
#pragma unroll
            for (int i = 0; i < NI; ++i) {
                const int r = wm + i * 16 + fm;
                const int sl = ((kh << 2) | quad) ^ (r & 7);
                af[i] = *(const short8*)&As[r * 64 + sl * 8];
            }
#pragma unroll
            for (int j = 0; j < NJ; ++j) {
                const int r = wn + j * 16 + fm;
                const int sl = ((kh << 2) | quad) ^ (r & 7);
                bf[j] = *(const short8*)&Bs[r * 64 + sl * 8];
            }
#pragma unroll
            for (int i = 0; i < NI; ++i)
#pragma unroll
                for (int j = 0; j < NJ; ++j)
                    acc[i][j] = __builtin_amdgcn_mfma_f32_16x16x32_bf16(
                        af[i], bf[j], acc[i][j], 0, 0, 0);
        }
    }

    // Epilogue. C/D layout: col = lane&15, row = quad*4 + reg.
#pragma unroll
    for (int j = 0; j < NJ; ++j) {
        const int col = col0 + wn + j * 16 + fm;
        const float bcol = (mode == 3 || mode == 4) ? 0.f : bias[col];
#pragma unroll
        for (int i = 0; i < NI; ++i) {
            const int rbase = row0 + wm + i * 16 + quad * 4;
#pragma unroll
            for (int r = 0; r < 4; ++r) {
                const int row = rbase + r;
                float val = acc[i][j][r] + ((mode == 3) ? bias[row] : bcol);
                if (mode == 1) val = fmaxf(val, 0.f);
                if (mode == 0 || mode == 4) Cf[(size_t)row * N + col] = val;
                else                        Cb[(size_t)row * N + col] = f2bf(val);
            }
        }
    }
}

template <int TM, int TN>
__global__ __launch_bounds__(256) void gemm_bf16_mfma(
    const unsigned short* __restrict__ A, const unsigned short* __restrict__ Bt,
    const float* __restrict__ bias, float* __restrict__ Cf,
    unsigned short* __restrict__ Cb, int M, int N, int K, int mode)
{
    __shared__ unsigned short As[TM * 64];
    __shared__ unsigned short Bs[TN * 64];
    gemm_body<TM, TN>(As, Bs, A, Bt, bias, Cf, Cb, M, N, K, mode,
                      blockIdx.x, blockIdx.y, 0, K);
}

// Split-K=2 GEMM with XCD row-striping: blocks [0,nbh) -> K low half -> C0
// (mode 0, bias); [nbh,2*nbh) -> high half -> C1 (mode 4). nbh % 8 == 0.
template <int TM, int TN>
__global__ __launch_bounds__(256) void gemm_splitk(
    const unsigned short* __restrict__ A, const unsigned short* __restrict__ Bt,
    const float* __restrict__ bias, float* __restrict__ C0,
    float* __restrict__ C1, int M, int N, int K,
    int nxh, int rows_per_xcd_h, int nbh)
{
    __shared__ unsigned short As[TM * 64];
    __shared__ unsigned short Bs[TN * 64];
    const int half = blockIdx.x >= nbh;
    const int r    = blockIdx.x - (half ? nbh : 0);
    const int xcd  = blockIdx.x & 7;
    const int idx  = r >> 3;
    const int bx   = idx % nxh;
    const int by   = xcd * rows_per_xcd_h + idx / nxh;
    const int kb   = half ? (K >> 1) : 0;
    gemm_body<TM, TN>(As, Bs, A, Bt, bias, half ? C1 : C0, nullptr,
                      M, N, K, half ? 4 : 0, bx, by, kb, kb + (K >> 1));
}

// Two independent GEMMs (same tile config) in one flat-grid dispatch.
template <int TM, int TN>
__global__ __launch_bounds__(256) void gemm_dual(
    const unsigned short* __restrict__ A0, const unsigned short* __restrict__ B0,
    const float* __restrict__ bias0, unsigned short* __restrict__ C0,
    int M0, int N0, int K0, int mode0, int nb0, int nx0,
    const unsigned short* __restrict__ A1, const unsigned short* __restrict__ B1,
    const float* __restrict__ bias1, unsigned short* __restrict__ C1,
    int M1, int N1, int K1, int mode1, int nx1)
{
    __shared__ unsigned short As[TM * 64];
    __shared__ unsigned short Bs[TN * 64];
    const int bid = blockIdx.x;
    if (bid < nb0) {
        gemm_body<TM, TN>(As, Bs, A0, B0, bias0, nullptr, C0,
                          M0, N0, K0, mode0, bid % nx0, bid / nx0, 0, K0);
    } else {
        const int t = bid - nb0;
        gemm_body<TM, TN>(As, Bs, A1, B1, bias1, nullptr, C1,
                          M1, N1, K1, mode1, t % nx1, t / nx1, 0, K1);
    }
}

// ---------------------------------------------------------------------------
// MFMA flash attention v3. qk: [4096][2048] bf16 (q cols 0..1023, k 1024..),
// vt: [1024][4096] bf16 (row = h*64+d, col = b*2048+t), a: [4096][1024] fp32.
// Q/K/V LDS = [64][64] shorts (hd=64 -> 128 B full-line rows), staged as
// 8-row x 128 B panels with both-sides XOR swizzle (R20 pattern).
// P pack via v_cvt_pk_bf16_f32 (R25): 8 instrs replace ~80 VALU ops.
// ---------------------------------------------------------------------------
__global__ __launch_bounds__(256) void fattn_mfma(
    const unsigned short* __restrict__ qk,
    const unsigned short* __restrict__ vt,
    float* __restrict__ a)
{
    const int T = 2048, LDQK = 2048, LDVT = 4096, OUTC = 1024;
    const float cs = 0.04508422f;       // (1/32) * log2(e)

    __shared__ unsigned short Qs[64 * 64];
    __shared__ unsigned short Ks[64 * 64];
    __shared__ unsigned short Vs[64 * 64];
    __shared__ unsigned short Ps[4][16][72];

    const int tid  = threadIdx.x;
    const int lane = tid & 63;
    const int w    = tid >> 6;
    const int fm   = lane & 15;
    const int quad = lane >> 4;
    const int srow = lane >> 3;                  // 0..7
    const int scol = ((lane & 7) ^ srow) << 3;   // swizzled col (shorts)

    const int n  = blockIdx.x;
    const int lo = n & 255, hi = n >> 8;
    const int h  = ((lo >> 5) & 7) | ((hi & 1) << 3);
    const int b  = hi >> 1;
    const int qv = lo & 31;
    const int u  = ((qv & 1) << 4) | ((qv & 2) << 2) | (qv & 4) |
                   ((qv & 8) >> 2) | ((qv & 16) >> 4);
    const int qb = (hi & 1) ? (31 - u) : u;
    const int q0 = qb * 64;

    const size_t rowbase = (size_t)b * T;

    // Q stage: 8 panels of 8 rows x 128 B; wave w stages panels w*2, w*2+1.
#pragma unroll
    for (int i = 0; i < 2; ++i) {
        const int p = w * 2 + i;
        const unsigned short* src = qk + (rowbase + q0 + p * 8 + srow) * LDQK
                                       + h * 64 + scol;
        __builtin_amdgcn_global_load_lds(
            (const __attribute__((address_space(1))) void*)src,
            (__attribute__((address_space(3))) void*)&Qs[p * 8 * 64], 16, 0, 0);
    }
    __syncthreads();
    const int qr = w * 16 + fm;
    short8 qf0 = *(const short8*)&Qs[qr * 64 + ((quad ^ (qr & 7)) << 3)];
    short8 qf1 = *(const short8*)&Qs[qr * 64 + (((4 | quad) ^ (qr & 7)) << 3)];

    short8 ones;
#pragma unroll
    for (int i = 0; i < 8; ++i) ones[i] = (short)0x3F80;   // bf16 1.0

    f32x4 o[4] = {};
    f32x4 lacc = {};

    const int qglob = q0 + w * 16 + fm;

    for (int jt = 0; jt <= qb; ++jt) {
        const int j0 = jt * 64;
        __syncthreads();
        // K: 8 panels, V: 8 panels; wave w stages units w*4 .. w*4+3.
#pragma unroll
        for (int i = 0; i < 4; ++i) {
            const int unit = w * 4 + i;          // wave-uniform
            if (unit < 8) {
                const unsigned short* ksrc = qk + (rowbase + j0 + unit * 8 + srow) * LDQK
                                                + 1024 + h * 64 + scol;
                __builtin_amdgcn_global_load_lds(
                    (const __attribute__((address_space(1))) void*)ksrc,
                    (__attribute__((address_space(3))) void*)&Ks[unit * 8 * 64], 16, 0, 0);
            } else {
                const int p = unit - 8;
                const unsigned short* vsrc = vt + (size_t)(h * 64 + p * 8 + srow) * LDVT
                                                + rowbase + j0 + scol;
                __builtin_amdgcn_global_load_lds(
                    (const __attribute__((address_space(1))) void*)vsrc,
                    (__attribute__((address_space(3))) void*)&Vs[p * 8 * 64], 16, 0, 0);
            }
        }
        __syncthreads();

        // S^T = K . Q^T
        f32x4 s[4];
#pragma unroll
        for (int j = 0; j < 4; ++j) {
            const int r = j * 16 + fm;
            short8 k0 = *(const short8*)&Ks[r * 64 + ((quad ^ (r & 7)) << 3)];
            short8 k1 = *(const short8*)&Ks[r * 64 + (((4 | quad) ^ (r & 7)) << 3)];
            f32x4 acc = {};
            acc = __builtin_amdgcn_mfma_f32_16x16x32_bf16(k0, qf0, acc, 0, 0, 0);
            acc = __builtin_amdgcn_mfma_f32_16x16x32_bf16(k1, qf1, acc, 0, 0, 0);
            s[j] = acc;
        }

        if (jt == qb) {
#pragma unroll
            for (int j = 0; j < 4; ++j) {
                const int kbase = j0 + j * 16 + quad * 4;
#pragma unroll
                for (int r = 0; r < 4; ++r) {
                    const float e = exp2f(s[j][r] * cs);
                    s[j][r] = (kbase + r > qglob) ? 0.f : e;
                }
            }
        } else {
#pragma unroll
            for (int j = 0; j < 4; ++j)
#pragma unroll
                for (int r = 0; r < 4; ++r)
                    s[j][r] = exp2f(s[j][r] * cs);
        }

        // P -> bf16 pack: v_cvt_pk_bf16_f32 (RNE), 2 f32 per instruction.
#pragma unroll
        for (int j = 0; j < 4; ++j) {
            unsigned d0, d1;
            asm("v_cvt_pk_bf16_f32 %0, %1, %2"
                : "=v"(d0) : "v"(s[j][0]), "v"(s[j][1]));
            asm("v_cvt_pk_bf16_f32 %0, %1, %2"
                : "=v"(d1) : "v"(s[j][2]), "v"(s[j][3]));
            *(uint2*)&Ps[w][fm][j * 16 + quad * 4] = make_uint2(d0, d1);
        }
        short8 pf0 = *(const short8*)&Ps[w][fm][quad * 8];
        short8 pf1 = *(const short8*)&Ps[w][fm][32 + quad * 8];

#pragma unroll
        for (int jd = 0; jd < 4; ++jd) {
            const int r = jd * 16 + fm;
            short8 v0 = *(const short8*)&Vs[r * 64 + ((quad ^ (r & 7)) << 3)];
            short8 v1 = *(const short8*)&Vs[r * 64 + (((4 | quad) ^ (r & 7)) << 3)];
            o[jd] = __builtin_amdgcn_mfma_f32_16x16x32_bf16(pf0, v0, o[jd], 0, 0, 0);
            o[jd] = __builtin_amdgcn_mfma_f32_16x16x32_bf16(pf1, v1, o[jd], 0, 0, 0);
        }
        lacc = __builtin_amdgcn_mfma_f32_16x16x32_bf16(pf0, ones, lacc, 0, 0, 0);
        lacc = __builtin_amdgcn_mfma_f32_16x16x32_bf16(pf1, ones, lacc, 0, 0, 0);
    }

    const size_t orow = rowbase + q0 + w * 16 + quad * 4;
#pragma unroll
    for (int r = 0; r < 4; ++r) {
        const float inv = 1.0f / lacc[r];
#pragma unroll
        for (int jd = 0; jd < 4; ++jd)
            a[(orow + r) * OUTC + h * 64 + jd * 16 + fm] = o[jd][r] * inv;
    }
}

// out = in (+ in2) + LayerNorm(in (+ in2))*w.
// bf16_out=1 -> write bf16 to outb, else fp32 outf. Wave-shuffle reduction.
__global__ __launch_bounds__(256) void add_ln_kernel(
    const float* __restrict__ in, const float* __restrict__ in2,
    const float* __restrict__ w,
    float* __restrict__ outf, unsigned short* __restrict__ outb, int bf16_out)
{
    const int C = 1024;
    const int row = blockIdx.x;
    const int tid = threadIdx.x;
    const int lane = tid & 63;
    const int wv   = tid >> 6;

    __shared__ float red[8];

    float4 xv = *(const float4*)(in + (size_t)row * C + tid * 4);
    if (in2) {
        float4 yv = *(const float4*)(in2 + (size_t)row * C + tid * 4);
        xv.x += yv.x; xv.y += yv.y; xv.z += yv.z; xv.w += yv.w;
    }

    float s = xv.x + xv.y + xv.z + xv.w;
#pragma unroll
    for (int o = 32; o > 0; o >>= 1) s += __shfl_xor(s, o, 64);
    if (lane == 0) red[wv] = s;
    __syncthreads();
    const float mu = (red[0] + red[1] + red[2] + red[3]) * (1.0f / 1024.0f);

    float dx = xv.x - mu, dy = xv.y - mu, dz = xv.z - mu, dw = xv.w - mu;
    float v = dx * dx + dy * dy + dz * dz + dw * dw;
#pragma unroll
    for (int o = 32; o > 0; o >>= 1) v += __shfl_xor(v, o, 64);
    if (lane == 0) red[4 + wv] = v;
    __syncthreads();
    const float rstd = rsqrtf((red[4] + red[5] + red[6] + red[7]) * (1.0f / 1024.0f)
                              + 1e-5f);

    float4 wvv = *(const float4*)(w + tid * 4);
    float ox = xv.x + dx * rstd * wvv.x;
    float oy = xv.y + dy * rstd * wvv.y;
    float oz = xv.z + dz * rstd * wvv.z;
    float ow = xv.w + dw * rstd * wvv.w;
    if (bf16_out) {
        ushort4 o4;
        o4.x = f2bf(ox); o4.y = f2bf(oy); o4.z = f2bf(oz); o4.w = f2bf(ow);
        *(ushort4*)(outb + (size_t)row * C + tid * 4) = o4;
    } else {
        *(float4*)(outf + (size_t)row * C + tid * 4) = make_float4(ox, oy, oz, ow);
    }
}

extern "C" void kernel_launch(void* const* d_in, const int* in_sizes, int n_in,
                              void* d_out, int out_size, void* d_ws, size_t ws_size,
                              hipStream_t stream)
{
    const float* x    = (const float*)d_in[0];
    const float* Wq   = (const float*)d_in[1];
    const float* bq   = (const float*)d_in[2];
    const float* Wk   = (const float*)d_in[3];
    const float* bk   = (const float*)d_in[4];
    const float* Wv   = (const float*)d_in[5];
    const float* bv   = (const float*)d_in[6];
    const float* W1   = (const float*)d_in[7];
    const float* b1   = (const float*)d_in[8];
    const float* W2   = (const float*)d_in[9];
    const float* b2   = (const float*)d_in[10];
    const float* ln_w = (const float*)d_in[11];
    float* out = (float*)d_out;
    char* ws = (char*)d_ws;

    const int B = 2, T = 2048, C = 1024, DFF = 4096;
    const int M = B * T;                 // 4096
    const size_t MB = 1048576;

    unsigned short* qk_bf = (unsigned short*)(ws);             // 16 MB [4096][2048]
    unsigned short* vt_bf = (unsigned short*)(ws + 16 * MB);   //  8 MB [1024][4096]
    float*          a     = (float*)(ws + 24 * MB);            // 16 MB [4096][1024]
    unsigned short* x_bf  = (unsigned short*)(ws + 40 * MB);   //  8 MB [4096][1024]
    unsigned short* Wqk_t = (unsigned short*)(ws + 48 * MB);   //  4 MB [2048][1024]
    unsigned short* Wvt   = (unsigned short*)(ws + 52 * MB);   //  2 MB [1024][1024]
    unsigned short* W1t   = (unsigned short*)(ws + 54 * MB);   //  8 MB [4096][1024]
    unsigned short* W2t   = (unsigned short*)(ws + 62 * MB);   //  8 MB [1024][4096]
    float*          bqk   = (float*)(ws + 70 * MB);            //  8 KB [2048]
    unsigned short* u_bf  = (unsigned short*)(ws + 71 * MB);   // 32 MB [4096][4096]
    unsigned short* h_bf  = x_bf;                              // reuse (x dead)
    float*          f     = (float*)(ws);                      // 16 MB, reuse qk (dead)
    float*          f2    = a;                                 // 16 MB, reuse a  (dead)

    dim3 blk(256);

    // One merged preprocessing dispatch (full-line transpose writes).
    prep_kernel<<<dim3(6920), blk, 0, stream>>>(
        x, Wq, Wk, Wv, W1, W2, bq, bk,
        x_bf, Wqk_t, Wvt, W1t, W2t, bqk);

    // QK projection + V^T in one dual dispatch, both <64,128> BK=64.
    gemm_dual<64, 128><<<dim3(1536), blk, 0, stream>>>(
        x_bf, Wqk_t, bqk, qk_bf, M, 2 * C, C, 2, 1024, 16,
        Wvt, x_bf, bv, vt_bf, C, M, C, 3, 32);

    fattn_mfma<<<dim3(1024), blk, 0, stream>>>(qk_bf, vt_bf, a);

    add_ln_kernel<<<dim3(M), blk, 0, stream>>>(a, nullptr, ln_w, nullptr, h_bf, 1);

    // FFN1: [4096,1024] x [1024,4096] -> relu -> bf16. <64,128> BK=64.
    gemm_bf16_mfma<64, 128><<<dim3(DFF / 128, M / 64), blk, 0, stream>>>(
        h_bf, W1t, b1, nullptr, u_bf, M, DFF, C, 1);

    // FFN2: [4096,4096] x [4096,1024] -> fp32, split-K=2. <128,64> BK=64,
    // 1024 blocks = 4/CU (512/half; per-half grid 16 cols x 32 rows,
    // 4 row-tiles per XCD). Partials f + f2 summed in the final add_ln.
    gemm_splitk<128, 64><<<dim3(1024), blk, 0, stream>>>(
        u_bf, W2t, b2, f, f2, M, C, DFF, 16, 4, 512);

    add_ln_kernel<<<dim3(M), blk, 0, stream>>>(f, f2, ln_w, out, nullptr, 0);
}